// Round 3
// baseline (1304.250 us; speedup 1.0000x reference)
//
#include <hip/hip_runtime.h>

#define CC 128     // channels
#define C4V 32     // float4 per row
#define RPB 1024   // rows per pool block
#define MAXB 300   // max segment boundaries handled by the fast path (global max is 255)

typedef float f4v __attribute__((ext_vector_type(4)));

__device__ __forceinline__ f4v vsplat(float x) {
    f4v r; r.x = x; r.y = x; r.z = x; r.w = x; return r;
}
__device__ __forceinline__ f4v vmax4(f4v a, f4v b) {
    f4v r;
    r.x = fmaxf(a.x, b.x); r.y = fmaxf(a.y, b.y);
    r.z = fmaxf(a.z, b.z); r.w = fmaxf(a.w, b.w);
    return r;
}

__device__ __forceinline__ unsigned fkey(float f) {
    unsigned b = __float_as_uint(f);
    return (b & 0x80000000u) ? ~b : (b | 0x80000000u);
}
__device__ __forceinline__ float fdec(unsigned k) {
    unsigned b = (k & 0x80000000u) ? (k & 0x7FFFFFFFu) : ~k;
    return __uint_as_float(b);
}

__device__ __forceinline__ void flush_seg(int seg, int c4, const f4v& sum, const f4v& mx,
                                          int cnt, float* __restrict__ seg_sum,
                                          unsigned* __restrict__ seg_maxk, int* __restrict__ seg_cnt) {
    float* sp = seg_sum + (size_t)seg * CC + c4 * 4;
    atomicAdd(sp + 0, sum.x);
    atomicAdd(sp + 1, sum.y);
    atomicAdd(sp + 2, sum.z);
    atomicAdd(sp + 3, sum.w);
    unsigned* mp = seg_maxk + (size_t)seg * CC + c4 * 4;
    atomicMax(mp + 0, fkey(mx.x));
    atomicMax(mp + 1, fkey(mx.y));
    atomicMax(mp + 2, fkey(mx.z));
    atomicMax(mp + 3, fkey(mx.w));
    if (c4 == 0) atomicAdd(&seg_cnt[seg], cnt);
}

__global__ void __launch_bounds__(256) pool_kernel(
    const float* __restrict__ feats, const int* __restrict__ ids, int N,
    float* __restrict__ seg_sum, unsigned* __restrict__ seg_maxk,
    int* __restrict__ seg_cnt)
{
    __shared__ int sids[RPB];
    __shared__ int bpos[MAXB + 1];
    __shared__ int nb;
    __shared__ f4v red_s[8][32];
    __shared__ f4v red_m[8][32];

    const int tid = threadIdx.x;
    const int c4 = tid & 31;   // which float4 of the row
    const int rl = tid >> 5;   // row-lane 0..7
    const long long r0 = (long long)blockIdx.x * RPB;
    const int nrows = (r0 + RPB <= (long long)N) ? RPB : (int)(N - r0);

    if (tid == 0) nb = 0;
    for (int i = tid; i < nrows; i += 256)
        sids[i] = ids[r0 + i];
    __syncthreads();

    // Find sub-segment boundaries inside this block's row range. ids are
    // globally sorted with <=256 distinct values, so NB is 1-3 in practice.
    for (int i = tid; i < nrows; i += 256) {
        if (i == 0 || sids[i] != sids[i - 1]) {
            int k = atomicAdd(&nb, 1);
            if (k < MAXB) bpos[k] = i;
        }
    }
    __syncthreads();
    const int NB = nb;

    if (NB <= MAXB) {
        if (tid == 0) {   // tiny insertion sort (NB ~ 1-3 in practice)
            for (int a = 1; a < NB; ++a) {
                int v = bpos[a]; int b = a - 1;
                while (b >= 0 && bpos[b] > v) { bpos[b + 1] = bpos[b]; --b; }
                bpos[b + 1] = v;
            }
            bpos[NB] = nrows;
        }
        __syncthreads();

        const f4v* fbase = (const f4v*)feats + (size_t)r0 * C4V + c4;

        for (int s = 0; s < NB; ++s) {
            const int lo  = bpos[s];
            const int hi  = bpos[s + 1];
            const int seg = sids[lo];
            const int len = hi - lo;

            f4v sum = vsplat(0.f);
            f4v mx  = vsplat(-3.4e38f);
            const f4v* p = fbase + (size_t)lo * C4V;

            // Branch-free, id-check-free accumulate: 8 independent 16B loads
            // in flight per thread (8 KB per wave).
            int j = rl;
            for (; j + 56 < len; j += 64) {
                f4v v[8];
                #pragma unroll
                for (int k = 0; k < 8; ++k)
                    v[k] = p[(size_t)(j + 8 * k) * C4V];
                #pragma unroll
                for (int k = 0; k < 8; ++k) {
                    sum += v[k];
                    mx = vmax4(mx, v[k]);
                }
            }
            for (; j < len; j += 8) {
                f4v v = p[(size_t)j * C4V];
                sum += v;
                mx = vmax4(mx, v);
            }

            // Reduce the 8 row-lanes in LDS, then ONE set of atomics per
            // (block, segment) issued by 32 lanes: ~12x fewer global atomics.
            red_s[rl][c4] = sum;
            red_m[rl][c4] = mx;
            __syncthreads();
            if (rl < 4) {
                red_s[rl][c4] += red_s[rl + 4][c4];
                red_m[rl][c4] = vmax4(red_m[rl][c4], red_m[rl + 4][c4]);
            }
            __syncthreads();
            if (rl < 2) {
                red_s[rl][c4] += red_s[rl + 2][c4];
                red_m[rl][c4] = vmax4(red_m[rl][c4], red_m[rl + 2][c4]);
            }
            __syncthreads();
            if (rl == 0) {
                f4v fs = red_s[0][c4] + red_s[1][c4];
                f4v fm = vmax4(red_m[0][c4], red_m[1][c4]);
                float* sp = seg_sum + (size_t)seg * CC + c4 * 4;
                atomicAdd(sp + 0, fs.x);
                atomicAdd(sp + 1, fs.y);
                atomicAdd(sp + 2, fs.z);
                atomicAdd(sp + 3, fs.w);
                unsigned* mp = seg_maxk + (size_t)seg * CC + c4 * 4;
                atomicMax(mp + 0, fkey(fm.x));
                atomicMax(mp + 1, fkey(fm.y));
                atomicMax(mp + 2, fkey(fm.z));
                atomicMax(mp + 3, fkey(fm.w));
                if (c4 == 0) atomicAdd(&seg_cnt[seg], len);
            }
            __syncthreads();   // red arrays reused next sub-segment
        }
    } else {
        // Fallback (pathological id pattern): per-row sequential with
        // per-thread flushes. Correct for any ids.
        f4v sum = vsplat(0.f);
        f4v mx  = vsplat(-3.4e38f);
        int cur = -1, cnt = 0;
        const f4v* fp = (const f4v*)feats + ((size_t)r0 + rl) * C4V + c4;
        for (int lr = rl; lr < nrows; lr += 8) {
            int id = sids[lr];
            f4v v = fp[(size_t)(lr - rl) * C4V];
            if (id != cur) {
                if (cur >= 0)
                    flush_seg(cur, c4, sum, mx, cnt, seg_sum, seg_maxk, seg_cnt);
                cur = id;
                sum = vsplat(0.f);
                mx  = vsplat(-3.4e38f);
                cnt = 0;
            }
            sum += v;
            mx = vmax4(mx, v);
            cnt++;
        }
        if (cur >= 0)
            flush_seg(cur, c4, sum, mx, cnt, seg_sum, seg_maxk, seg_cnt);
    }
}

__global__ void __launch_bounds__(128) head_kernel(
    const float* __restrict__ seg_sum, const unsigned* __restrict__ seg_maxk,
    const int* __restrict__ seg_cnt,
    const float* __restrict__ W1, const float* __restrict__ b1,
    const float* __restrict__ W2, const float* __restrict__ b2,
    const float* __restrict__ W3, const float* __restrict__ b3,
    const float* __restrict__ W4, const float* __restrict__ b4,
    float* __restrict__ out)
{
    __shared__ float pooled[2 * CC];
    __shared__ float h1s[128];
    __shared__ float h2s[64];
    __shared__ float h3s[32];

    const int b = blockIdx.x;
    const int t = threadIdx.x;   // 0..127

    const int cnt = seg_cnt[b];
    const float inv = (cnt > 0) ? (1.f / (float)cnt) : 0.f;

    {
        float s = seg_sum[(size_t)b * CC + t];
        unsigned k = seg_maxk[(size_t)b * CC + t];
        pooled[t] = s * inv;                              // 0 for empty segments
        pooled[CC + t] = (cnt > 0) ? fdec(k) : 0.f;
    }
    __syncthreads();

    {   // 256 -> 128
        float acc = b1[t];
        for (int i = 0; i < 2 * CC; i++) acc += pooled[i] * W1[i * 128 + t];
        h1s[t] = fmaxf(acc, 0.f);
    }
    __syncthreads();

    if (t < 64) {   // 128 -> 64
        float acc = b2[t];
        for (int i = 0; i < 128; i++) acc += h1s[i] * W2[i * 64 + t];
        h2s[t] = fmaxf(acc, 0.f);
    }
    __syncthreads();

    if (t < 32) {   // 64 -> 32
        float acc = b3[t];
        for (int i = 0; i < 64; i++) acc += h2s[i] * W3[i * 32 + t];
        h3s[t] = fmaxf(acc, 0.f);
    }
    __syncthreads();

    if (t < 4) {    // 32 -> 4
        float acc = b4[t];
        for (int i = 0; i < 32; i++) acc += h3s[i] * W4[i * 4 + t];
        out[b * 4 + t] = acc;
    }
}

extern "C" void kernel_launch(void* const* d_in, const int* in_sizes, int n_in,
                              void* d_out, int out_size, void* d_ws, size_t ws_size,
                              hipStream_t stream) {
    const float* feats = (const float*)d_in[0];
    const int*   ids   = (const int*)d_in[1];
    // d_in[2] = batch_size scalar (on device; value derived from out_size instead)
    const float* W1 = (const float*)d_in[3];
    const float* b1 = (const float*)d_in[4];
    const float* W2 = (const float*)d_in[5];
    const float* b2 = (const float*)d_in[6];
    const float* W3 = (const float*)d_in[7];
    const float* b3 = (const float*)d_in[8];
    const float* W4 = (const float*)d_in[9];
    const float* b4 = (const float*)d_in[10];
    float* out = (float*)d_out;

    const int N = in_sizes[1];
    const int NCLS = in_sizes[10];         // 4
    const int B = out_size / NCLS;         // 256

    float*    seg_sum  = (float*)d_ws;
    unsigned* seg_maxk = (unsigned*)(seg_sum + (size_t)B * CC);
    int*      seg_cnt  = (int*)(seg_maxk + (size_t)B * CC);
    const size_t init_bytes = (size_t)B * CC * 4 * 2 + (size_t)B * 4;
    hipMemsetAsync(d_ws, 0, init_bytes, stream);

    const int grid = (N + RPB - 1) / RPB;
    pool_kernel<<<grid, 256, 0, stream>>>(feats, ids, N, seg_sum, seg_maxk, seg_cnt);
    head_kernel<<<B, 128, 0, stream>>>(seg_sum, seg_maxk, seg_cnt,
                                       W1, b1, W2, b2, W3, b3, W4, b4, out);
}